// Round 7
// baseline (142.584 us; speedup 1.0000x reference)
//
#include <hip/hip_runtime.h>
#include <cstdint>
#include <cstddef>

// Problem constants (match reference)
#define BATCH 16
#define NBLK 16
#define TB 256
#define EMBED 2048
#define NKV 8
#define GQ 4          // group size = NH / NKV
#define HD 64
#define NQROWS 3072   // 2048 (q) + 512 (k_cur) + 512 (v_cur)
#define TTOT 4096     // NBLK * TB
#define QSCALE 0.18033688011112042f  // 64^-0.5 * log2(e)
#define NEGBIG (-1e30f)

// Workspace layout (floats):
#define OFF_PARTM  49152      // [512][128]
#define OFF_PARTS  114688     // [512][128]
#define OFF_CMB    180224     // [512] float4
#define OFF_PARTO  182272     // [512][32][HD]
#define OFF_ATTEN  1230848    // [16][2048]
#define OFF_S      1263616    // [128][TTOT][GQ]

__device__ __forceinline__ float dot4(float4 a, float4 b) {
  return a.x * b.x + a.y * b.y + a.z * b.z + a.w * b.w;
}

template <int CTRL>
__device__ __forceinline__ float dpp_add(float x) {
  return x + __int_as_float(
                 __builtin_amdgcn_mov_dpp(__float_as_int(x), CTRL, 0xF, 0xF, true));
}

// ---------------------------------------------------------------------------
// Kernel 1: fused q/k/v projection.  proj[b][i] = dot(W_all[i], x[b])
// ---------------------------------------------------------------------------
#define PROJ_RPB 4
__global__ __launch_bounds__(256) void proj_kernel(
    const float* __restrict__ x, const float* __restrict__ Wq,
    const float* __restrict__ Wk, const float* __restrict__ Wv,
    float* __restrict__ proj) {
  int tid = threadIdx.x;
  int bb = tid & 15, kc = tid >> 4;
  int row0 = blockIdx.x * PROJ_RPB;
  const float* xp = x + (size_t)bb * EMBED + kc * 128;
  const float* wr[PROJ_RPB];
#pragma unroll
  for (int r = 0; r < PROJ_RPB; ++r) {
    int row = row0 + r;
    wr[r] = (row < 2048 ? Wq + (size_t)row * EMBED
             : row < 2560 ? Wk + (size_t)(row - 2048) * EMBED
                          : Wv + (size_t)(row - 2560) * EMBED) + kc * 128;
  }
  float a[PROJ_RPB] = {0.f, 0.f, 0.f, 0.f};
#pragma unroll
  for (int k = 0; k < 128; k += 8) {
    float4 x0 = *reinterpret_cast<const float4*>(xp + k);
    float4 x1 = *reinterpret_cast<const float4*>(xp + k + 4);
#pragma unroll
    for (int r = 0; r < PROJ_RPB; ++r) {
      float4 w0 = *reinterpret_cast<const float4*>(wr[r] + k);
      float4 w1 = *reinterpret_cast<const float4*>(wr[r] + k + 4);
      a[r] += dot4(w0, x0) + dot4(w1, x1);
    }
  }
  int w = tid >> 6, lane = tid & 63;
  __shared__ float red[4][PROJ_RPB][16];
#pragma unroll
  for (int r = 0; r < PROJ_RPB; ++r) {
    float s = a[r];
    s += __shfl_xor(s, 16);
    s += __shfl_xor(s, 32);
    if (lane < 16) red[w][r][lane] = s;
  }
  __syncthreads();
  if (tid < 16 * PROJ_RPB) {
    int r = tid >> 4, b2 = tid & 15;
    float v = red[0][r][b2] + red[1][r][b2] + red[2][r][b2] + red[3][r][b2];
    proj[(size_t)b2 * NQROWS + row0 + r] = v;
  }
}

// ---------------------------------------------------------------------------
// Kernel 2: score pass — burst-load K stream, deferred (max,sumexp).
// Grid (32, BATCH, NKV) x 256; each wave owns 32 tokens (8 KB burst).
// 4 lanes per token (16 dims each). Inner loop: dot4 + 2 DPP + store only.
// ---------------------------------------------------------------------------
__global__ __launch_bounds__(256) void score_kernel(
    const float* __restrict__ blocks_k, const float* __restrict__ proj,
    const int* __restrict__ last_offset, float* __restrict__ sbuf,
    float* __restrict__ part_m, float* __restrict__ part_s) {
  int tb2 = blockIdx.x, b = blockIdx.y, h = blockIdx.z;
  int nb = tb2 >> 1;
  int tid = threadIdx.x;
  int w = tid >> 6, lane = tid & 63;
  int tq = lane >> 2;        // token within 16-token group
  int qd = lane & 3;         // quad position: dims [qd*16, qd*16+16)
  int valid = (nb == NBLK - 1) ? last_offset[0] : TB;
  int tok0 = (tb2 & 1) * 128 + w * 32;  // wave's first token in cache block

  // q fragments: 16 dims per lane for each of the 4 query heads
  float4 qv[GQ][4];
  const float* qbase = proj + (size_t)b * NQROWS + h * GQ * HD + qd * 16;
#pragma unroll
  for (int gi = 0; gi < GQ; ++gi)
#pragma unroll
    for (int j = 0; j < 4; ++j)
      qv[gi][j] = *reinterpret_cast<const float4*>(qbase + gi * HD + j * 4);

  const float* kg = blocks_k + (((size_t)nb * BATCH + b) * NKV + h) * (TB * HD);

  // burst: 8 independent wave-loads (8 KB) issued before any consumption
  float4 kr[2][4];
#pragma unroll
  for (int i = 0; i < 2; ++i) {
    const float* kp = kg + (size_t)(tok0 + i * 16 + tq) * HD + qd * 16;
#pragma unroll
    for (int j = 0; j < 4; ++j)
      kr[i][j] = *reinterpret_cast<const float4*>(kp + j * 4);
  }
  __builtin_amdgcn_sched_barrier(0);

  float s[2][GQ];
#pragma unroll
  for (int i = 0; i < 2; ++i) {
#pragma unroll
    for (int gi = 0; gi < GQ; ++gi) {
      float t = dot4(qv[gi][0], kr[i][0]) + dot4(qv[gi][1], kr[i][1]) +
                dot4(qv[gi][2], kr[i][2]) + dot4(qv[gi][3], kr[i][3]);
      t = dpp_add<0xB1>(t);  // quad_perm xor 1
      t = dpp_add<0x4E>(t);  // quad_perm xor 2
      s[i][gi] = (tok0 + i * 16 + tq) < valid ? t : NEGBIG;
    }
  }

  // store raw scores: [t][gi] layout, 256 B dense per wave-store
  float* sout = sbuf + ((size_t)(b * NKV + h)) * (TTOT * GQ) +
                (size_t)(nb * TB + tok0) * GQ;
#pragma unroll
  for (int i = 0; i < 2; ++i) {
    float v01 = (qd & 1) ? s[i][1] : s[i][0];
    float v23 = (qd & 1) ? s[i][3] : s[i][2];
    sout[(size_t)(i * 16) * GQ + lane] = (qd & 2) ? v23 : v01;
  }

  // deferred (max, sumexp) over the wave's 32 tokens: register 2-pass + tree
#pragma unroll
  for (int gi = 0; gi < GQ; ++gi) {
    float mx = fmaxf(s[0][gi], s[1][gi]);
#pragma unroll
    for (int mask = 4; mask < 64; mask <<= 1)
      mx = fmaxf(mx, __shfl_xor(mx, mask));
    float sm = exp2f((s[0][gi] - mx) * QSCALE) + exp2f((s[1][gi] - mx) * QSCALE);
#pragma unroll
    for (int mask = 4; mask < 64; mask <<= 1) sm += __shfl_xor(sm, mask);
    if (lane == 0) {
      size_t wi = (size_t)(b * NKV + h) * GQ + gi;
      part_m[wi * 128 + tb2 * 4 + w] = mx;
      part_s[wi * 128 + tb2 * 4 + w] = sm;
    }
  }
}

// ---------------------------------------------------------------------------
// Kernel 3: combine 128 wave-partials + current-token score per (b,h,gi).
// Grid: 128 blocks x 256; one wave per (b,h,gi). cmb = {M, p_cur, 1/T, 0}.
// ---------------------------------------------------------------------------
__global__ __launch_bounds__(256) void combine_kernel(
    const float* __restrict__ proj, const float* __restrict__ part_m,
    const float* __restrict__ part_s, float4* __restrict__ cmb) {
  int tid = threadIdx.x;
  int wi = blockIdx.x * 4 + (tid >> 6);
  int lane = tid & 63;
  int b = wi >> 5;
  int h = (wi >> 2) & 7;
  int gi = wi & 3;

  float pm_a = part_m[(size_t)wi * 128 + lane];
  float pm_b = part_m[(size_t)wi * 128 + 64 + lane];
  float ps_a = part_s[(size_t)wi * 128 + lane];
  float ps_b = part_s[(size_t)wi * 128 + 64 + lane];

  // current-token raw score: q[b,h,gi,:] . k_cur[b,h,:]
  float qd = proj[(size_t)b * NQROWS + (h * GQ + gi) * HD + lane];
  float kd = proj[(size_t)b * NQROWS + 2048 + h * HD + lane];
  float sp = qd * kd;
#pragma unroll
  for (int mask = 1; mask < 64; mask <<= 1) sp += __shfl_xor(sp, mask);

  float M = fmaxf(pm_a, pm_b);
#pragma unroll
  for (int mask = 1; mask < 64; mask <<= 1) M = fmaxf(M, __shfl_xor(M, mask));
  M = fmaxf(M, sp);

  float contrib = ps_a * exp2f((pm_a - M) * QSCALE) +
                  ps_b * exp2f((pm_b - M) * QSCALE);
#pragma unroll
  for (int mask = 1; mask < 64; mask <<= 1) contrib += __shfl_xor(contrib, mask);
  float p_cur = exp2f((sp - M) * QSCALE);
  if (lane == 0) cmb[wi] = make_float4(M, p_cur, 1.f / (contrib + p_cur), 0.f);
}

// ---------------------------------------------------------------------------
// Kernel 4: PV pass — burst-load V stream; p on the fly from raw scores.
// Grid (32, BATCH, NKV) x 256; each wave owns 32 tokens (8 KB V burst).
// 16 lanes per token (4 dims each). Inner loop: exp + FMA only.
// ---------------------------------------------------------------------------
__global__ __launch_bounds__(256) void pv_kernel(
    const float* __restrict__ blocks_v, const float* __restrict__ sbuf,
    const float4* __restrict__ cmb, float* __restrict__ part_o) {
  int tb2 = blockIdx.x, b = blockIdx.y, h = blockIdx.z;
  int nb = tb2 >> 1;
  int tid = threadIdx.x;
  int w = tid >> 6, lane = tid & 63;
  int sub = lane >> 4, dl = (lane & 15) * 4;
  int tok0 = (tb2 & 1) * 128 + w * 32;

  const float* vg = blocks_v + (((size_t)nb * BATCH + b) * NKV + h) * (TB * HD);
  const float* sg = sbuf + ((size_t)(b * NKV + h)) * (TTOT * GQ) +
                    (size_t)(nb * TB + tok0) * GQ;

  float Mv[GQ];
#pragma unroll
  for (int gi = 0; gi < GQ; ++gi)
    Mv[gi] = cmb[(size_t)(b * NKV + h) * GQ + gi].x;

  // burst: 8 x 1KB V loads, then 8 score loads (L2/L3-hot)
  float4 vr[8], sr[8];
#pragma unroll
  for (int i = 0; i < 8; ++i)
    vr[i] = *reinterpret_cast<const float4*>(
        vg + (size_t)(tok0 + i * 4 + sub) * HD + dl);
#pragma unroll
  for (int i = 0; i < 8; ++i)
    sr[i] = *reinterpret_cast<const float4*>(sg + (size_t)(i * 4 + sub) * GQ);
  __builtin_amdgcn_sched_barrier(0);

  float4 acc[GQ];
#pragma unroll
  for (int gi = 0; gi < GQ; ++gi) acc[gi] = make_float4(0.f, 0.f, 0.f, 0.f);

#pragma unroll
  for (int i = 0; i < 8; ++i) {
    float p0 = exp2f((sr[i].x - Mv[0]) * QSCALE);
    float p1 = exp2f((sr[i].y - Mv[1]) * QSCALE);
    float p2 = exp2f((sr[i].z - Mv[2]) * QSCALE);
    float p3 = exp2f((sr[i].w - Mv[3]) * QSCALE);
    acc[0].x += p0 * vr[i].x; acc[0].y += p0 * vr[i].y;
    acc[0].z += p0 * vr[i].z; acc[0].w += p0 * vr[i].w;
    acc[1].x += p1 * vr[i].x; acc[1].y += p1 * vr[i].y;
    acc[1].z += p1 * vr[i].z; acc[1].w += p1 * vr[i].w;
    acc[2].x += p2 * vr[i].x; acc[2].y += p2 * vr[i].y;
    acc[2].z += p2 * vr[i].z; acc[2].w += p2 * vr[i].w;
    acc[3].x += p3 * vr[i].x; acc[3].y += p3 * vr[i].y;
    acc[3].z += p3 * vr[i].z; acc[3].w += p3 * vr[i].w;
  }

  // merge the 4 token sub-slots (plain adds)
#pragma unroll
  for (int mask = 16; mask <= 32; mask <<= 1) {
#pragma unroll
    for (int gi = 0; gi < GQ; ++gi) {
      acc[gi].x += __shfl_xor(acc[gi].x, mask);
      acc[gi].y += __shfl_xor(acc[gi].y, mask);
      acc[gi].z += __shfl_xor(acc[gi].z, mask);
      acc[gi].w += __shfl_xor(acc[gi].w, mask);
    }
  }

  __shared__ float lds_o[4][GQ][HD];
  if (lane < 16) {
#pragma unroll
    for (int gi = 0; gi < GQ; ++gi)
      *reinterpret_cast<float4*>(&lds_o[w][gi][dl]) = acc[gi];
  }
  __syncthreads();
  if (w == 0) {
    int d = lane;
#pragma unroll
    for (int gi = 0; gi < GQ; ++gi) {
      float o = lds_o[0][gi][d] + lds_o[1][gi][d] + lds_o[2][gi][d] + lds_o[3][gi][d];
      part_o[(((size_t)(b * NKV + h) * GQ + gi) * 32 + tb2) * HD + d] = o;
    }
  }
}

// ---------------------------------------------------------------------------
// Kernel 5: merge 32 block partials + current token, normalize.
// Grid: 128 blocks x 256; one wave per (b,h,gi).
// ---------------------------------------------------------------------------
__global__ __launch_bounds__(256) void reduce_kernel(
    const float* __restrict__ proj, const float* __restrict__ part_o,
    const float4* __restrict__ cmb, float* __restrict__ atten) {
  int tid = threadIdx.x;
  int wi = blockIdx.x * 4 + (tid >> 6);
  int lane = tid & 63;  // head-dim d
  int b = wi >> 5;
  int h = (wi >> 2) & 7;
  int gi = wi & 3;
  size_t pidx = (size_t)wi * 32;

  float4 c4 = cmb[wi];
  float vd = proj[(size_t)b * NQROWS + 2560 + h * HD + lane];
  float o = c4.y * vd;
#pragma unroll
  for (int s2 = 0; s2 < 32; ++s2) o += part_o[(pidx + s2) * HD + lane];
  atten[(size_t)b * EMBED + (h * GQ + gi) * HD + lane] = o * c4.z;
}

// ---------------------------------------------------------------------------
// Kernel 6: out[b][i] = dot(Wo[i], atten[b])
// ---------------------------------------------------------------------------
#define OUT_RPB 4
__global__ __launch_bounds__(256) void out_kernel(
    const float* __restrict__ atten, const float* __restrict__ Wo,
    float* __restrict__ out) {
  int tid = threadIdx.x;
  int bb = tid & 15, kc = tid >> 4;
  int row0 = blockIdx.x * OUT_RPB;
  const float* xp = atten + (size_t)bb * EMBED + kc * 128;
  float a[OUT_RPB] = {0.f, 0.f, 0.f, 0.f};
#pragma unroll
  for (int k = 0; k < 128; k += 8) {
    float4 x0 = *reinterpret_cast<const float4*>(xp + k);
    float4 x1 = *reinterpret_cast<const float4*>(xp + k + 4);
#pragma unroll
    for (int r = 0; r < OUT_RPB; ++r) {
      const float* wp = Wo + (size_t)(row0 + r) * EMBED + kc * 128;
      float4 w0 = *reinterpret_cast<const float4*>(wp + k);
      float4 w1 = *reinterpret_cast<const float4*>(wp + k + 4);
      a[r] += dot4(w0, x0) + dot4(w1, x1);
    }
  }
  int w = tid >> 6, lane = tid & 63;
  __shared__ float red[4][OUT_RPB][16];
#pragma unroll
  for (int r = 0; r < OUT_RPB; ++r) {
    float s = a[r];
    s += __shfl_xor(s, 16);
    s += __shfl_xor(s, 32);
    if (lane < 16) red[w][r][lane] = s;
  }
  __syncthreads();
  if (tid < 16 * OUT_RPB) {
    int r = tid >> 4, b2 = tid & 15;
    float v = red[0][r][b2] + red[1][r][b2] + red[2][r][b2] + red[3][r][b2];
    out[(size_t)b2 * EMBED + row0 + r] = v;
  }
}

// ---------------------------------------------------------------------------
extern "C" void kernel_launch(void* const* d_in, const int* in_sizes, int n_in,
                              void* d_out, int out_size, void* d_ws, size_t ws_size,
                              hipStream_t stream) {
  const float* x = (const float*)d_in[0];
  const float* bk = (const float*)d_in[1];
  const float* bv = (const float*)d_in[2];
  const float* Wq = (const float*)d_in[3];
  const float* Wk = (const float*)d_in[4];
  const float* Wv = (const float*)d_in[5];
  const float* Wo = (const float*)d_in[6];
  const int* lo = (const int*)d_in[7];

  float* ws = (float*)d_ws;
  float* proj = ws;
  float* part_m = ws + OFF_PARTM;
  float* part_s = ws + OFF_PARTS;
  float4* cmb = (float4*)(ws + OFF_CMB);
  float* part_o = ws + OFF_PARTO;
  float* atten = ws + OFF_ATTEN;
  float* sbuf = ws + OFF_S;
  float* out = (float*)d_out;

  proj_kernel<<<NQROWS / PROJ_RPB, 256, 0, stream>>>(x, Wq, Wk, Wv, proj);
  score_kernel<<<dim3(32, BATCH, NKV), 256, 0, stream>>>(bk, proj, lo, sbuf,
                                                         part_m, part_s);
  combine_kernel<<<(BATCH * NKV * GQ) / 4, 256, 0, stream>>>(proj, part_m,
                                                             part_s, cmb);
  pv_kernel<<<dim3(32, BATCH, NKV), 256, 0, stream>>>(bv, sbuf, cmb, part_o);
  reduce_kernel<<<(BATCH * NKV * GQ) / 4, 256, 0, stream>>>(proj, part_o, cmb,
                                                            atten);
  out_kernel<<<EMBED / OUT_RPB, 256, 0, stream>>>(atten, Wo, out);
}

// Round 9
// 114.086 us; speedup vs baseline: 1.2498x; 1.2498x over previous
//
#include <hip/hip_runtime.h>
#include <cstdint>
#include <cstddef>

// Problem constants (match reference)
#define BATCH 16
#define NBLK 16
#define TB 256
#define EMBED 2048
#define NKV 8
#define GQ 4          // group size = NH / NKV = 32/8
#define HD 64
#define NQROWS 3072   // 2048 (q) + 512 (k_cur) + 512 (v_cur)
#define QSCALE 0.18033688011112042f  // 64^-0.5 * log2(e); scores in log2 domain

// Workspace layout (floats):
#define OFF_PARTMS 49152
#define OFF_PARTO  65536
#define OFF_ATTEN  589824

__device__ __forceinline__ float dot4(float4 a, float4 b) {
  return a.x * b.x + a.y * b.y + a.z * b.z + a.w * b.w;
}

// Nontemporal 16B load: stream KV without L3 allocation (one-touch data).
// __builtin_nontemporal_load needs a native vector type, not HIP float4.
typedef float f32x4_t __attribute__((ext_vector_type(4)));
__device__ __forceinline__ float4 ntload4(const float* p) {
  f32x4_t v = __builtin_nontemporal_load(reinterpret_cast<const f32x4_t*>(p));
  return make_float4(v.x, v.y, v.z, v.w);
}

// DPP-based sum over each 16-lane group (pure VALU, no LDS pipe).
template <int CTRL>
__device__ __forceinline__ float dpp_add(float x) {
  return x + __int_as_float(
                 __builtin_amdgcn_mov_dpp(__float_as_int(x), CTRL, 0xF, 0xF, true));
}
__device__ __forceinline__ float red16(float x) {
  x = dpp_add<0xB1>(x);   // quad_perm xor 1
  x = dpp_add<0x4E>(x);   // quad_perm xor 2
  x = dpp_add<0x124>(x);  // row_ror:4
  x = dpp_add<0x128>(x);  // row_ror:8
  return x;
}

// ---------------------------------------------------------------------------
// Kernel 1: fused q/k/v projection.  proj[b][i] = dot(W_all[i], x[b])
// ---------------------------------------------------------------------------
#define PROJ_RPB 4
__global__ __launch_bounds__(256) void proj_kernel(
    const float* __restrict__ x, const float* __restrict__ Wq,
    const float* __restrict__ Wk, const float* __restrict__ Wv,
    float* __restrict__ proj) {
  int tid = threadIdx.x;
  int bb = tid & 15, kc = tid >> 4;
  int row0 = blockIdx.x * PROJ_RPB;
  const float* xp = x + (size_t)bb * EMBED + kc * 128;
  const float* wr[PROJ_RPB];
#pragma unroll
  for (int r = 0; r < PROJ_RPB; ++r) {
    int row = row0 + r;
    wr[r] = (row < 2048 ? Wq + (size_t)row * EMBED
             : row < 2560 ? Wk + (size_t)(row - 2048) * EMBED
                          : Wv + (size_t)(row - 2560) * EMBED) + kc * 128;
  }
  float a[PROJ_RPB] = {0.f, 0.f, 0.f, 0.f};
#pragma unroll
  for (int k = 0; k < 128; k += 8) {
    float4 x0 = *reinterpret_cast<const float4*>(xp + k);
    float4 x1 = *reinterpret_cast<const float4*>(xp + k + 4);
#pragma unroll
    for (int r = 0; r < PROJ_RPB; ++r) {
      float4 w0 = *reinterpret_cast<const float4*>(wr[r] + k);
      float4 w1 = *reinterpret_cast<const float4*>(wr[r] + k + 4);
      a[r] += dot4(w0, x0) + dot4(w1, x1);
    }
  }
  int w = tid >> 6, lane = tid & 63;
  __shared__ float red[4][PROJ_RPB][16];
#pragma unroll
  for (int r = 0; r < PROJ_RPB; ++r) {
    float s = a[r];
    s += __shfl_xor(s, 16);
    s += __shfl_xor(s, 32);
    if (lane < 16) red[w][r][lane] = s;
  }
  __syncthreads();
  if (tid < 16 * PROJ_RPB) {
    int r = tid >> 4, b2 = tid & 15;
    float v = red[0][r][b2] + red[1][r][b2] + red[2][r][b2] + red[3][r][b2];
    proj[(size_t)b2 * NQROWS + row0 + r] = v;
  }
}

// ---------------------------------------------------------------------------
// Kernel 2: fused flash-decode partials, one KV-cache block per workgroup.
// r2 structure (best measured) + nontemporal K/V loads (no L3 allocation).
// ---------------------------------------------------------------------------
template <bool MASKED>
__device__ __forceinline__ void batch16(const float4 qv[GQ], const float4 kv[4],
                                        const float4 vv[4], const bool pr[4],
                                        float m[GQ], float sm[GQ], float4 acc[GQ]) {
  float s[4][GQ];
#pragma unroll
  for (int j = 0; j < 4; ++j)
#pragma unroll
    for (int gi = 0; gi < GQ; ++gi) s[j][gi] = dot4(qv[gi], kv[j]);
#pragma unroll
  for (int j = 0; j < 4; ++j)
#pragma unroll
    for (int gi = 0; gi < GQ; ++gi) {
      s[j][gi] = red16(s[j][gi]);
      if (MASKED && !pr[j]) s[j][gi] = -1e30f;
    }
#pragma unroll
  for (int gi = 0; gi < GQ; ++gi) {
    float bm = fmaxf(fmaxf(s[0][gi], s[1][gi]), fmaxf(s[2][gi], s[3][gi]));
    float mn = fmaxf(m[gi], bm);
    float c = exp2f(m[gi] - mn);
    float p0 = exp2f(s[0][gi] - mn);
    float p1 = exp2f(s[1][gi] - mn);
    float p2 = exp2f(s[2][gi] - mn);
    float p3 = exp2f(s[3][gi] - mn);
    sm[gi] = sm[gi] * c + ((p0 + p1) + (p2 + p3));
    acc[gi].x = acc[gi].x * c + (p0 * vv[0].x + p1 * vv[1].x + p2 * vv[2].x + p3 * vv[3].x);
    acc[gi].y = acc[gi].y * c + (p0 * vv[0].y + p1 * vv[1].y + p2 * vv[2].y + p3 * vv[3].y);
    acc[gi].z = acc[gi].z * c + (p0 * vv[0].z + p1 * vv[1].z + p2 * vv[2].z + p3 * vv[3].z);
    acc[gi].w = acc[gi].w * c + (p0 * vv[0].w + p1 * vv[1].w + p2 * vv[2].w + p3 * vv[3].w);
    m[gi] = mn;
  }
}

__global__ __launch_bounds__(256) void attn_partial_kernel(
    const float* __restrict__ blocks_k, const float* __restrict__ blocks_v,
    const float* __restrict__ proj, const int* __restrict__ last_offset,
    float* __restrict__ part_ms, float* __restrict__ part_o) {
  int nb = blockIdx.x, b = blockIdx.y, h = blockIdx.z;
  int tid = threadIdx.x;
  int w = tid >> 6, lane = tid & 63;
  int sub = lane >> 4, dl = (lane & 15) * 4;

  // q fragments, pre-scaled by 1/sqrt(d) * log2(e) (log2-domain softmax)
  float4 qv[GQ];
  const float* qbase = proj + (size_t)b * NQROWS + h * GQ * HD + dl;
#pragma unroll
  for (int gi = 0; gi < GQ; ++gi) {
    float4 q = *reinterpret_cast<const float4*>(qbase + gi * HD);
    qv[gi] = make_float4(q.x * QSCALE, q.y * QSCALE, q.z * QSCALE, q.w * QSCALE);
  }

  size_t kvoff = (((size_t)nb * BATCH + b) * NKV + h) * (size_t)(TB * HD);
  const float* kp = blocks_k + kvoff + (size_t)(w * 64 + sub) * HD + dl;
  const float* vp = blocks_v + kvoff + (size_t)(w * 64 + sub) * HD + dl;

  float m[GQ], sm[GQ];
  float4 acc[GQ];
#pragma unroll
  for (int gi = 0; gi < GQ; ++gi) {
    m[gi] = -1e30f;
    sm[gi] = 0.f;
    acc[gi] = make_float4(0.f, 0.f, 0.f, 0.f);
  }

  if (nb != NBLK - 1) {
    bool pr[4] = {true, true, true, true};
#pragma unroll
    for (int ot = 0; ot < 4; ++ot) {
      float4 kv[4], vv[4];
#pragma unroll
      for (int j = 0; j < 4; ++j)
        kv[j] = ntload4(kp + (ot * 16 + j * 4) * HD);
#pragma unroll
      for (int j = 0; j < 4; ++j)
        vv[j] = ntload4(vp + (ot * 16 + j * 4) * HD);
      batch16<false>(qv, kv, vv, pr, m, sm, acc);
    }
  } else {
    int valid = last_offset[0];
#pragma unroll
    for (int ot = 0; ot < 4; ++ot) {
      float4 kv[4], vv[4];
      bool pr[4];
#pragma unroll
      for (int j = 0; j < 4; ++j) {
        int tok = w * 64 + ot * 16 + j * 4 + sub;
        pr[j] = tok < valid;
        kv[j] = make_float4(0.f, 0.f, 0.f, 0.f);
        vv[j] = make_float4(0.f, 0.f, 0.f, 0.f);
        if (pr[j]) {
          kv[j] = ntload4(kp + (ot * 16 + j * 4) * HD);
          vv[j] = ntload4(vp + (ot * 16 + j * 4) * HD);
        }
      }
      batch16<true>(qv, kv, vv, pr, m, sm, acc);
    }
  }

  // merge the 4 token sub-slots (lane bits 4,5)
#pragma unroll
  for (int mask = 16; mask <= 32; mask <<= 1) {
#pragma unroll
    for (int gi = 0; gi < GQ; ++gi) {
      float mo = __shfl_xor(m[gi], mask);
      float so = __shfl_xor(sm[gi], mask);
      float4 ao;
      ao.x = __shfl_xor(acc[gi].x, mask);
      ao.y = __shfl_xor(acc[gi].y, mask);
      ao.z = __shfl_xor(acc[gi].z, mask);
      ao.w = __shfl_xor(acc[gi].w, mask);
      float mn = fmaxf(m[gi], mo);
      float c1 = exp2f(m[gi] - mn);
      float c2 = exp2f(mo - mn);
      sm[gi] = sm[gi] * c1 + so * c2;
      acc[gi].x = acc[gi].x * c1 + ao.x * c2;
      acc[gi].y = acc[gi].y * c1 + ao.y * c2;
      acc[gi].z = acc[gi].z * c1 + ao.z * c2;
      acc[gi].w = acc[gi].w * c1 + ao.w * c2;
      m[gi] = mn;
    }
  }

  // cross-wave merge via LDS
  __shared__ float lds_o[4][GQ][HD];
  __shared__ float lds_m[4][GQ];
  __shared__ float lds_s[4][GQ];
  if (lane < 16) {
#pragma unroll
    for (int gi = 0; gi < GQ; ++gi)
      *reinterpret_cast<float4*>(&lds_o[w][gi][dl]) = acc[gi];
    if (lane == 0) {
#pragma unroll
      for (int gi = 0; gi < GQ; ++gi) {
        lds_m[w][gi] = m[gi];
        lds_s[w][gi] = sm[gi];
      }
    }
  }
  __syncthreads();

  if (w == 0) {
    int d = lane;  // 0..63
#pragma unroll
    for (int gi = 0; gi < GQ; ++gi) {
      float M = fmaxf(fmaxf(lds_m[0][gi], lds_m[1][gi]),
                      fmaxf(lds_m[2][gi], lds_m[3][gi]));
      float sum = 0.f, o = 0.f;
#pragma unroll
      for (int ww = 0; ww < 4; ++ww) {
        float c = exp2f(lds_m[ww][gi] - M);
        sum += lds_s[ww][gi] * c;
        o += lds_o[ww][gi][d] * c;
      }
      size_t idx = (((size_t)b * NKV + h) * GQ + gi) * NBLK + nb;
      if (lane == 0) {
        part_ms[idx * 2] = M;
        part_ms[idx * 2 + 1] = sum;
      }
      part_o[idx * HD + d] = o;
    }
  }
}

// ---------------------------------------------------------------------------
// Kernel 3: merge 16 block-partials + current token per (b,h,gi) (log2 domain).
// ---------------------------------------------------------------------------
__global__ __launch_bounds__(256) void reduce_kernel(
    const float* __restrict__ proj, const float* __restrict__ part_ms,
    const float* __restrict__ part_o, float* __restrict__ atten) {
  int tid = threadIdx.x;
  int wi = blockIdx.x * 4 + (tid >> 6);
  int lane = tid & 63;  // head-dim d
  int b = wi >> 5;
  int h = (wi >> 2) & 7;
  int gi = wi & 3;
  size_t pidx = (((size_t)b * NKV + h) * GQ + gi) * NBLK;

  float qd = proj[(size_t)b * NQROWS + (h * GQ + gi) * HD + lane];
  float kd = proj[(size_t)b * NQROWS + 2048 + h * HD + lane];
  float vd = proj[(size_t)b * NQROWS + 2560 + h * HD + lane];
  float sp = qd * kd;
#pragma unroll
  for (int mask = 1; mask < 64; mask <<= 1) sp += __shfl_xor(sp, mask);
  float s_cur = sp * QSCALE;  // log2 domain

  float pm[NBLK], ps[NBLK];
  float M = s_cur;
#pragma unroll
  for (int nb = 0; nb < NBLK; ++nb) {
    pm[nb] = part_ms[(pidx + nb) * 2];
    ps[nb] = part_ms[(pidx + nb) * 2 + 1];
    M = fmaxf(M, pm[nb]);
  }
  float p_cur = exp2f(s_cur - M);
  float sum = p_cur;
  float o = p_cur * vd;
#pragma unroll
  for (int nb = 0; nb < NBLK; ++nb) {
    float c = exp2f(pm[nb] - M);
    sum += ps[nb] * c;
    o += part_o[(pidx + nb) * HD + lane] * c;
  }
  atten[(size_t)b * EMBED + (h * GQ + gi) * HD + lane] = o / sum;
}

// ---------------------------------------------------------------------------
// Kernel 4: out[b][i] = dot(Wo[i], atten[b])
// ---------------------------------------------------------------------------
#define OUT_RPB 4
__global__ __launch_bounds__(256) void out_kernel(
    const float* __restrict__ atten, const float* __restrict__ Wo,
    float* __restrict__ out) {
  int tid = threadIdx.x;
  int bb = tid & 15, kc = tid >> 4;
  int row0 = blockIdx.x * OUT_RPB;
  const float* xp = atten + (size_t)bb * EMBED + kc * 128;
  float a[OUT_RPB] = {0.f, 0.f, 0.f, 0.f};
#pragma unroll
  for (int k = 0; k < 128; k += 8) {
    float4 x0 = *reinterpret_cast<const float4*>(xp + k);
    float4 x1 = *reinterpret_cast<const float4*>(xp + k + 4);
#pragma unroll
    for (int r = 0; r < OUT_RPB; ++r) {
      const float* wp = Wo + (size_t)(row0 + r) * EMBED + kc * 128;
      float4 w0 = *reinterpret_cast<const float4*>(wp + k);
      float4 w1 = *reinterpret_cast<const float4*>(wp + k + 4);
      a[r] += dot4(w0, x0) + dot4(w1, x1);
    }
  }
  int w = tid >> 6, lane = tid & 63;
  __shared__ float red[4][OUT_RPB][16];
#pragma unroll
  for (int r = 0; r < OUT_RPB; ++r) {
    float s = a[r];
    s += __shfl_xor(s, 16);
    s += __shfl_xor(s, 32);
    if (lane < 16) red[w][r][lane] = s;
  }
  __syncthreads();
  if (tid < 16 * OUT_RPB) {
    int r = tid >> 4, b2 = tid & 15;
    float v = red[0][r][b2] + red[1][r][b2] + red[2][r][b2] + red[3][r][b2];
    out[(size_t)b2 * EMBED + row0 + r] = v;
  }
}

// ---------------------------------------------------------------------------
extern "C" void kernel_launch(void* const* d_in, const int* in_sizes, int n_in,
                              void* d_out, int out_size, void* d_ws, size_t ws_size,
                              hipStream_t stream) {
  const float* x = (const float*)d_in[0];
  const float* bk = (const float*)d_in[1];
  const float* bv = (const float*)d_in[2];
  const float* Wq = (const float*)d_in[3];
  const float* Wk = (const float*)d_in[4];
  const float* Wv = (const float*)d_in[5];
  const float* Wo = (const float*)d_in[6];
  const int* lo = (const int*)d_in[7];

  float* ws = (float*)d_ws;
  float* proj = ws;
  float* part_ms = ws + OFF_PARTMS;
  float* part_o = ws + OFF_PARTO;
  float* atten = ws + OFF_ATTEN;
  float* out = (float*)d_out;

  proj_kernel<<<NQROWS / PROJ_RPB, 256, 0, stream>>>(x, Wq, Wk, Wv, proj);
  attn_partial_kernel<<<dim3(NBLK, BATCH, NKV), 256, 0, stream>>>(
      bk, bv, proj, lo, part_ms, part_o);
  reduce_kernel<<<(BATCH * NKV * GQ) / 4, 256, 0, stream>>>(
      proj, part_ms, part_o, atten);
  out_kernel<<<EMBED / OUT_RPB, 256, 0, stream>>>(atten, Wo, out);
}